// Round 5
// baseline (5667.136 us; speedup 1.0000x reference)
//
#include <hip/hip_runtime.h>
#include <hip/hip_bf16.h>
#include <hip/hip_cooperative_groups.h>

namespace cg = cooperative_groups;

// Problem constants
#define Hdim 1024
#define Nb   2048
#define Lsteps 48

// GEMM tile: BM n-rows x 32 j-cols x 4 gates (B-tile 128 rows), BK=64.
#define BM 256
#define BROWS 128
#define NT 16              // K-tiles (1024/64)

typedef unsigned short ushort_t;
typedef short bf16x8 __attribute__((ext_vector_type(8)));
typedef float f32x4 __attribute__((ext_vector_type(4)));

typedef __attribute__((address_space(3))) unsigned int lds_u32;
typedef const __attribute__((address_space(1))) unsigned int glb_u32;

__device__ __forceinline__ void gll16(const void* g, void* l) {
    __builtin_amdgcn_global_load_lds((glb_u32*)g, (lds_u32*)l, 16, 0, 0);
}

__device__ __forceinline__ ushort_t f2bf(float x) {
    unsigned u = __builtin_bit_cast(unsigned, x);
    unsigned r = u + 0x7fffu + ((u >> 16) & 1u);
    return (ushort_t)(r >> 16);
}

__device__ __forceinline__ float frcp(float x) { return __builtin_amdgcn_rcpf(x); }
__device__ __forceinline__ float fsigmoid(float x) { return frcp(1.0f + __expf(-x)); }
__device__ __forceinline__ float ftanh(float x) {
    float xm = fminf(fmaxf(x, -15.0f), 15.0f);
    float e = __expf(2.0f * xm);
    return (e - 1.0f) * frcp(e + 1.0f);
}

__device__ __forceinline__ f32x4 mfma16(bf16x8 a, bf16x8 b, f32x4 c) {
    return __builtin_amdgcn_mfma_f32_16x16x32_bf16(a, b, c, 0, 0, 0);
}

#define VMCNT6   asm volatile("s_waitcnt vmcnt(6)"  ::: "memory")
#define VMCNT0   asm volatile("s_waitcnt vmcnt(0)"  ::: "memory")
#define LGKMCNT0 asm volatile("s_waitcnt lgkmcnt(0)" ::: "memory")

// ---------------------------------------------------------------------------
// Prep kernels
// ---------------------------------------------------------------------------
__global__ __launch_bounds__(256) void prep_w(const float* __restrict__ W,
                                              ushort_t* __restrict__ Wb) {
    int i = blockIdx.x * 256 + threadIdx.x;
    Wb[i] = f2bf(W[i]);
}

__global__ __launch_bounds__(256) void prep_h(const float* __restrict__ h_in,
                                              ushort_t* __restrict__ h0,
                                              const float* __restrict__ b_ih,
                                              const float* __restrict__ b_hh,
                                              float* __restrict__ bias) {
    int i = blockIdx.x * 256 + threadIdx.x;
    h0[i] = f2bf(h_in[i]);
    if (i < 4 * Hdim) bias[i] = b_ih[i] + b_hh[i];
}

// ---------------------------------------------------------------------------
// Persistent cooperative kernel: ONE launch runs all 48 steps.
// 256 blocks x 512 threads (8 waves), 1 block/CU (96 KB LDS), co-resident.
//
// Why: 4 K-loop schedule variants landed within 9% -> per-step cost is
// dominated by per-launch fixed overhead (dispatch boundary, pipeline
// cold-fill, cst register-death). Persistence removes: 48 launch boundaries,
// the entire cst buffer (cell state lives in cpre[16] VGPRs for all 48
// steps), the cst memset, and per-step bias reloads.
//
// Cross-step correctness: epilogue writes hdst -> __threadfence() (device
// scope, cross-XCD per G16) -> grid.sync() -> next step reads. Flush phase
// reads all blocks' tmp writes (covered by same fence+sync); a second
// grid.sync() after flush closes the WAR hazard on tmp slot reuse (the
// kernel boundary used to provide this).
//
// K-loop: round-4-verified depth-2 counted-vmcnt pipeline (6 gll/stage/wave:
// 4 A + 2 B; vmcnt(6) = exactly one tile in flight). Buffer reuse across
// steps is safe: all buf reads are consumed by MFMAs before each wave
// reaches grid.sync (operand wait implies ds_read retirement).
// ---------------------------------------------------------------------------
__global__ __launch_bounds__(512) void lstm_all(
    ushort_t* __restrict__ hA,           // [Nb][Hdim] bf16 (initial h, from prep)
    ushort_t* __restrict__ hB,           // [Nb][Hdim] bf16 (ping-pong)
    const ushort_t* __restrict__ Wb,     // [4*Hdim][Hdim] bf16
    const float* __restrict__ bias,      // [4*Hdim]
    float* __restrict__ tmp16,           // [16][Nb][Hdim] f32 h slots
    float* __restrict__ out)             // [Nb][Hdim][Lsteps] f32
{
    extern __shared__ __align__(16) ushort_t smem[];
    ushort_t* As = smem;                       // [2][BM*64]    64 KB
    ushort_t* Bs = smem + 2 * (BM * 64);       // [2][BROWS*64] 32 KB

    cg::grid_group grid = cg::this_grid();

    const int tid  = threadIdx.x;
    const int lane = tid & 63;
    const int wid  = tid >> 6;            // 0..7
    const int wr   = wid >> 1;            // n quarter (0..3)
    const int wc   = wid & 1;             // j half (0..1)

    // XCD-aware remap: p%8 = XCD, 32 slots per XCD (round-4 verified).
    const int p    = blockIdx.x;
    const int xcd  = p & 7;
    const int slot = p >> 3;
    const int jb   = (xcd >> 1) * 8 + (slot & 7);   // 0..31
    const int nb   = (xcd & 1) * 4 + (slot >> 3);   // 0..7
    const int n0   = nb * BM;
    const int j0   = jb * 32;

    const int lr   = lane & 15;
    const int q4   = (lane >> 4) * 4;
    const int j    = j0 + wc * 16 + lr;

    // bias: loaded ONCE for all 48 steps
    const float bi = bias[j];
    const float bf = bias[Hdim + j];
    const float bg = bias[2 * Hdim + j];
    const float bo = bias[3 * Hdim + j];

    // cell state: lives in registers for the entire sequence (c0 = 0)
    float cpre[16];
#pragma unroll
    for (int i = 0; i < 16; ++i) cpre[i] = 0.0f;

    // staging geometry (round-4 verified)
    const int srow8  = lane >> 3;
    const int schunk = (lane & 7) ^ srow8;
    const int choff  = schunk * 8;
    const size_t aOff = (size_t)(n0 + wid * 32 + srow8) * Hdim + choff;
    const ushort_t* bGlob =
        Wb + (size_t)((wid >> 1) * Hdim + j0 + (wid & 1) * 16 + srow8) * Hdim + choff;

    const int rsw  = lr & 7;
    const int cq   = lane >> 4;

#pragma unroll 1
    for (int t = 0; t < Lsteps; ++t) {
        const ushort_t* hsrc = (t & 1) ? hB : hA;
        ushort_t*       hdst = (t & 1) ? hA : hB;
        float* tslot = tmp16 + (size_t)(t & 15) * (Nb * Hdim);
        const ushort_t* aGlob = hsrc + aOff;

        f32x4 acc[4][4];
#pragma unroll
        for (int g = 0; g < 4; ++g)
#pragma unroll
            for (int ri = 0; ri < 4; ++ri)
                acc[g][ri] = (f32x4){0.f, 0.f, 0.f, 0.f};

        auto STAGE = [&](int buf, int it) {
            const int k0 = it * 64;
#pragma unroll
            for (int ii = 0; ii < 4; ++ii)
                gll16(aGlob + (size_t)ii * 8 * Hdim + k0,
                      &As[buf * (BM * 64) + (wid * 32 + ii * 8) * 64]);
#pragma unroll
            for (int ii = 0; ii < 2; ++ii)
                gll16(bGlob + (size_t)ii * 8 * Hdim + k0,
                      &Bs[buf * (BROWS * 64) + (wid * 16 + ii * 8) * 64]);
        };

        auto COMPUTE = [&](int buf) {
#pragma unroll
            for (int kh = 0; kh < 2; ++kh) {
                const int ch = ((cq + kh * 4) ^ rsw) * 8;
                bf16x8 af[4], bfr[4];
#pragma unroll
                for (int ri = 0; ri < 4; ++ri) {
                    int row = wr * 64 + ri * 16 + lr;
                    af[ri] = *(const bf16x8*)&As[buf * (BM * 64) + row * 64 + ch];
                }
#pragma unroll
                for (int g = 0; g < 4; ++g) {
                    int u = g * 32 + wc * 16 + lr;
                    bfr[g] = *(const bf16x8*)&Bs[buf * (BROWS * 64) + u * 64 + ch];
                }
#pragma unroll
                for (int g = 0; g < 4; ++g)
#pragma unroll
                    for (int ri = 0; ri < 4; ++ri)
                        acc[g][ri] = mfma16(af[ri], bfr[g], acc[g][ri]);
            }
        };

        // ---- depth-2 counted-vmcnt pipeline over 16 K-tiles ----
        STAGE(0, 0); STAGE(1, 1);            // 12 gll in flight/wave
#pragma unroll 1
        for (int tt = 0; tt < NT; ++tt) {
            const int cur = tt & 1;
            if (tt < NT - 1) { VMCNT6; } else { VMCNT0; }
            __builtin_amdgcn_s_barrier();
            __builtin_amdgcn_s_setprio(1);
            COMPUTE(cur);
            __builtin_amdgcn_s_setprio(0);
            if (tt < NT - 2) {
                LGKMCNT0;
                __builtin_amdgcn_s_barrier();
                STAGE(cur, tt + 2);
            }
        }

        // ---- epilogue: C/D layout col=lane&15, row=(lane>>4)*4+reg ----
#pragma unroll
        for (int ri = 0; ri < 4; ++ri)
#pragma unroll
            for (int q = 0; q < 4; ++q) {
                int n = n0 + wr * 64 + ri * 16 + q4 + q;
                float gi = fsigmoid(acc[0][ri][q] + bi);
                float gf = fsigmoid(acc[1][ri][q] + bf);
                float gg = ftanh(acc[2][ri][q] + bg);
                float go = fsigmoid(acc[3][ri][q] + bo);
                size_t idx = (size_t)n * Hdim + j;
                float cn = gf * cpre[ri * 4 + q] + gi * gg;
                cpre[ri * 4 + q] = cn;               // stays in VGPRs
                float hv = go * ftanh(cn);
                hdst[idx] = f2bf(hv);
                tslot[idx] = hv;
            }

        __threadfence();                     // device-scope: cross-XCD visibility
        grid.sync();

        if ((t & 15) == 15) {
            // ---- integrated flush: tmp[16][Nb*Hdim] -> out[idx][t0..t0+16] ----
            const int t0 = t - 15;
            const int gth = blockIdx.x * 512 + tid;      // 0..131071
#pragma unroll 1
            for (int u = 0; u < 16; ++u) {
                int idx = u * 131072 + gth;
                float v[16];
#pragma unroll
                for (int s = 0; s < 16; ++s)
                    v[s] = tmp16[(size_t)s * (Nb * Hdim) + idx];
                float4* dst = (float4*)(out + (size_t)idx * Lsteps + t0);
#pragma unroll
                for (int s = 0; s < 4; ++s)
                    dst[s] = make_float4(v[4 * s], v[4 * s + 1], v[4 * s + 2], v[4 * s + 3]);
            }
            grid.sync();                     // WAR: slot 0 reused next step
        }
    }
}

// ---------------------------------------------------------------------------
extern "C" void kernel_launch(void* const* d_in, const int* in_sizes, int n_in,
                              void* d_out, int out_size, void* d_ws, size_t ws_size,
                              hipStream_t stream) {
    const float* h_in = (const float*)d_in[0];
    const float* W    = (const float*)d_in[1];
    const float* b_ih = (const float*)d_in[2];
    const float* b_hh = (const float*)d_in[3];
    float* out = (float*)d_out;

    // Workspace layout (bytes):
    //   Wb     @ 0          : 4096*1024*2 = 8388608
    //   h0     @ 8388608    : 2048*1024*2 = 4194304
    //   h1     @ 12582912   : 2048*1024*2 = 4194304
    //   bias   @ 16777216   : 4096*4      = 16384
    //   tmp16  @ 16793600   : 16*2048*1024*4 = 134217728
    char* ws = (char*)d_ws;
    ushort_t* Wb   = (ushort_t*)(ws);
    ushort_t* h0   = (ushort_t*)(ws + 8388608);
    ushort_t* h1   = (ushort_t*)(ws + 12582912);
    float*    bias = (float*)(ws + 16777216);
    float*    tmp16= (float*)(ws + 16793600);

    const int smem_bytes = 2 * (BM * 64 + BROWS * 64) * (int)sizeof(ushort_t); // 96 KB
    static bool attr_done = false;
    if (!attr_done) {
        hipFuncSetAttribute((const void*)lstm_all,
                            hipFuncAttributeMaxDynamicSharedMemorySize, smem_bytes);
        attr_done = true;
    }

    prep_w<<<(4 * Hdim * Hdim) / 256, 256, 0, stream>>>(W, Wb);
    prep_h<<<(Nb * Hdim) / 256, 256, 0, stream>>>(h_in, h0, b_ih, b_hh, bias);

    void* kargs[] = { (void*)&h0, (void*)&h1, (void*)&Wb, (void*)&bias,
                      (void*)&tmp16, (void*)&out };
    hipLaunchCooperativeKernel((const void*)lstm_all, dim3(256), dim3(512),
                               kargs, smem_bytes, stream);
}